// Round 1
// 99.808 us; speedup vs baseline: 1.0095x; 1.0095x over previous
//
#include <hip/hip_runtime.h>
#include <math.h>

#define DIM 4096
#define ROWS 2048
#define SB 72   // LDS image row stride in halves: %8==0 -> 16B-aligned ds_read_b128
                // frag loads. Row stride 144B: frag-read addr mod 128B = 16*((n+q)&7)
                // -> 8 lanes per 16B slot = minimum aliasing (conflict-free);
                // b64 writes land on 8*((2n+q)&15) -> 4 lanes/slot, also min.

typedef _Float16 half8  __attribute__((ext_vector_type(8)));
typedef _Float16 half4  __attribute__((ext_vector_type(4)));
typedef float    float4e __attribute__((ext_vector_type(4)));

// ---- pre-kernel: gt[64b+a] = (g_mu + softplus(g_rho)*eps)[64a+b]
// TRANSPOSED 64x64 image of g, so the mid-kernel g-multiply (which now holds
// Z, not Z^T, in acc) keeps r-contiguous float4 loads with the same index
// expression as before.
__global__ void g_precompute(const float* __restrict__ eps,
                             const float* __restrict__ g_mu,
                             const float* __restrict__ g_rho,
                             float* __restrict__ gt) {
    int i = blockIdx.x * blockDim.x + threadIdx.x;
    gt[((i & 63) << 6) | (i >> 6)] = fmaf(log1pf(expf(g_rho[i])), eps[i], g_mu[i]);
}

// Load the 8 MFMA fragments of the 64x64 image with the contraction dim
// CONTIGUOUS: frag[F][Kt][j] = img[16F+n][32Kt+8q+j] -> one ds_read_b128 each
// (8 per stage, was 64 scalar ds_read_u16). Serves as:
//   stage-R: A-frag(I=F):  A[m=16F+n][k=32Kt+8q+j]      (A-layout m=lane&15, k=8q+j)
//   stage-L: B-frag(J=F):  B[k][n'=16F+n] = S[n'][k]    (B-layout n=lane&15, k=8q+j)
__device__ __forceinline__ void load_frags(const _Float16* __restrict__ img,
                                           int n, int q, half8 frag[4][2]) {
#pragma unroll
    for (int F = 0; F < 4; ++F)
#pragma unroll
        for (int Kt = 0; Kt < 2; ++Kt)
            frag[F][Kt] = *(const half8*)(img + (16 * F + n) * SB + 32 * Kt + 8 * q);
}

// stage-R: C = S * H   (image row-major as A; H fragments as B, valid because
// H is symmetric: Hf[J][Kt][j] = H[16J+n][32Kt+8q+j] = H[32Kt+8q+j][16J+n]).
__device__ __forceinline__ void mul_H_right(const half8 frag[4][2], const half8 Hf[4][2],
                                            float4e acc[4][4]) {
#pragma unroll
    for (int I = 0; I < 4; ++I)
#pragma unroll
        for (int J = 0; J < 4; ++J) {
            float4e c = {0.0f, 0.0f, 0.0f, 0.0f};
            c = __builtin_amdgcn_mfma_f32_16x16x32_f16(frag[I][0], Hf[J][0], c, 0, 0, 0);
            c = __builtin_amdgcn_mfma_f32_16x16x32_f16(frag[I][1], Hf[J][1], c, 0, 0, 0);
            acc[I][J] = c;
        }
}

// stage-L: C = H * S^T  (H as A; image col-major as B).
__device__ __forceinline__ void mul_H_left(const half8 frag[4][2], const half8 Hf[4][2],
                                           float4e acc[4][4]) {
#pragma unroll
    for (int I = 0; I < 4; ++I)
#pragma unroll
        for (int J = 0; J < 4; ++J) {
            float4e c = {0.0f, 0.0f, 0.0f, 0.0f};
            c = __builtin_amdgcn_mfma_f32_16x16x32_f16(Hf[I][0], frag[J][0], c, 0, 0, 0);
            c = __builtin_amdgcn_mfma_f32_16x16x32_f16(Hf[I][1], frag[J][1], c, 0, 0, 0);
            acc[I][J] = c;
        }
}

// Write acc (C-layout: row=16I+4q+r, col=16J+n [m89]) TRANSPOSED to the image:
// img[col][row] -> image = C^T. 4 contiguous rows -> one 8B half4 write.
__device__ __forceinline__ void img_write_T(_Float16* __restrict__ img,
                                            int n, int q, const float4e acc[4][4]) {
#pragma unroll
    for (int I = 0; I < 4; ++I)
#pragma unroll
        for (int J = 0; J < 4; ++J) {
            half4 h;
            h[0] = (_Float16)acc[I][J][0];
            h[1] = (_Float16)acc[I][J][1];
            h[2] = (_Float16)acc[I][J][2];
            h[3] = (_Float16)acc[I][J][3];
            *(half4*)(img + (16 * J + n) * SB + 16 * I + 4 * q) = h;
        }
}

// One wave per row. FWHT_4096 = H64 (x) H64: with V[a][b] = v[64a+b],
// FWHT(v) = H.V.H. Alternating-side schedule (all LDS frag reads b128):
//   S0 = V                         (row-major img0)
//   R:  C1 = V.H        -> S1 = (V.H)^T   = H.V^T
//   L:  C2 = H.S1^T     = H.V.H = Z       (FWHT1 done, in acc)
//   acc *= G (gt transposed image: gt[64col+row], r-contiguous)
//   -> S2 = Z'^T
//   R:  C3 = Z'^T.H     -> S3 = (Z'^T.H)^T = H.Z'
//   L:  C4 = H.S3^T     = H.Z'^T.H = Y^T   (FWHT2 done)
//   out[e] = s1[e] * Y^T element, e = 1024J+64n+16I+4q+r (unchanged).
// Wave-private image: NO barriers (per-wave DS pipe is in-order).
__global__ void __launch_bounds__(256, 2)
whvi_mfma(const float* __restrict__ x, const float* __restrict__ s1,
          const float* __restrict__ s2, const float* __restrict__ gt,
          float* __restrict__ out) {
    const int lane = threadIdx.x & 63;
    const int wid  = threadIdx.x >> 6;
    const int row  = blockIdx.x * 4 + wid;     // 512 blocks x 4 waves = 2048 rows
    const int n = lane & 15, q = lane >> 4;

    __shared__ __align__(16) _Float16 lds[4 * 64 * SB];   // 36 KB/block
    _Float16* __restrict__ img = lds + wid * 64 * SB;     // wave-private

    const float4e* __restrict__ xr  = (const float4e*)(x + (size_t)row * DIM);
    const float4e* __restrict__ s2v = (const float4e*)s2;

    // ---- issue row loads first (32 b128 in flight)
    float4e xv[16], sv[16];
#pragma unroll
    for (int r = 0; r < 16; ++r) xv[r] = xr[64 * r + lane];
#pragma unroll
    for (int r = 0; r < 16; ++r) sv[r] = s2v[64 * r + lane];

    // ---- H fragments (A-layout: m=lane&15, k=8q+j [m120]); overlaps load latency
    half8 Hf[4][2];
#pragma unroll
    for (int I = 0; I < 4; ++I)
#pragma unroll
        for (int Kt = 0; Kt < 2; ++Kt) {
            half8 h;
#pragma unroll
            for (int j = 0; j < 8; ++j) {
                int rr = 16 * I + n, cc = 32 * Kt + 8 * q + j;
                h[j] = (__popc(rr & cc) & 1) ? (_Float16)(-1.0f) : (_Float16)(1.0f);
            }
            Hf[I][Kt] = h;
        }

    // ---- IMG0 = V = s2*x: element e=256r+4*lane+i -> img[(4r+q)*SB + 4n + i]
#pragma unroll
    for (int r = 0; r < 16; ++r) {
        float4e p = xv[r] * sv[r];
        half4 h;
        h[0] = (_Float16)p[0]; h[1] = (_Float16)p[1];
        h[2] = (_Float16)p[2]; h[3] = (_Float16)p[3];
        *(half4*)(img + (4 * r + q) * SB + 4 * n) = h;
    }

    half8   frag[4][2];
    float4e acc[4][4];

    load_frags(img, n, q, frag);
    mul_H_right(frag, Hf, acc);          // C1 = V.H
    img_write_T(img, n, q, acc);         // S1 = H.V^T   (in-order DS: safe reuse)

    load_frags(img, n, q, frag);
    mul_H_left(frag, Hf, acc);           // C2 = Z = H.V.H

    // ---- g multiply: acc holds Z (row=16I+4q+r, col=16J+n);
    // G[row][col] = gt[64col+row] = gt[1024J+64n+16I+4q+r], r contiguous b128.
#pragma unroll
    for (int I = 0; I < 4; ++I)
#pragma unroll
        for (int J = 0; J < 4; ++J) {
            const float4e gg = *(const float4e*)(gt + 1024 * J + 64 * n + 16 * I + 4 * q);
            acc[I][J] *= gg;
        }

    img_write_T(img, n, q, acc);         // S2 = Z'^T
    load_frags(img, n, q, frag);
    mul_H_right(frag, Hf, acc);          // C3 = Z'^T.H
    img_write_T(img, n, q, acc);         // S3 = H.Z'
    load_frags(img, n, q, frag);
    mul_H_left(frag, Hf, acc);           // C4 = Y^T

    // ---- s1 scale + store: e = 1024J + 64n + 16I + 4q (+r): b128, line-covered
    float* __restrict__ orow = out + (size_t)row * DIM;
#pragma unroll
    for (int I = 0; I < 4; ++I)
#pragma unroll
        for (int J = 0; J < 4; ++J) {
            const int e = 1024 * J + 64 * n + 16 * I + 4 * q;
            const float4e sg = *(const float4e*)(s1 + e);
            *(float4e*)(orow + e) = acc[I][J] * sg;
        }
}

extern "C" void kernel_launch(void* const* d_in, const int* in_sizes, int n_in,
                              void* d_out, int out_size, void* d_ws, size_t ws_size,
                              hipStream_t stream) {
    // setup_inputs order: x, epsilon, s1, s2, g_mu, g_rho
    const float* x     = (const float*)d_in[0];
    const float* eps   = (const float*)d_in[1];
    const float* s1    = (const float*)d_in[2];
    const float* s2    = (const float*)d_in[3];
    const float* g_mu  = (const float*)d_in[4];
    const float* g_rho = (const float*)d_in[5];
    float* out = (float*)d_out;
    float* gt  = (float*)d_ws;   // 4096 floats, transposed 64x64 g image

    g_precompute<<<DIM / 256, 256, 0, stream>>>(eps, g_mu, g_rho, gt);
    whvi_mfma<<<ROWS / 4, 256, 0, stream>>>(x, s1, s2, gt, out);
}